// Round 7
// baseline (53.281 us; speedup 1.0000x reference)
//
#include <hip/hip_runtime.h>

// PillarFeatureNet fused, single feature read, pipelined:
//  K1 pfn_main: per-wave run of pillars; double-buffered LDS staging with
//     next-pillar prefetch; per-pillar raw extrema (max&min, channel pairs
//     packed f32x2); BN moments via per-lane decomposition:
//       Q1[4],Q2[10]  raw valid-point moments (per-lane)
//       S[4][5]       sum_k s_partial(k,lane) (x) o(k)   (per-lane!)
//       U1[5],U2[15]  sum_k nv*o, nv*o(x)o    (wave-uniform, lane0)
//     where o(k) = (-mx,-my,-mz,-cx,-cy). Only 3 shfl-reductions per pillar
//     (the all-P mean sums). Deterministic block partials, no atomics.
//  K2 pfn_finalize: reduce 54 partial rows, assemble augmented moments,
//     per-channel scale/shift.
//  K3 pfn_apply: pick extremum by sign(scale), BN affine + relu.
// features [K,P,4] f32, num_voxels [K] i32, coors [K,4] i32,
// W [9,64] f32, gamma/beta [64] f32 -> out [K,64] f32.

typedef float f32x2 __attribute__((ext_vector_type(2)));

#define NR 54  // partial rows: 4 Q1 + 10 Q2 + 20 S + 5 U1 + 15 U2

__device__ __forceinline__ float wred_add(float v) {
#pragma unroll
  for (int off = 1; off < 64; off <<= 1) v += __shfl_xor(v, off, 64);
  return v;
}
__device__ __forceinline__ f32x2 pmax2(f32x2 a, f32x2 b) {
  f32x2 r; r.x = fmaxf(a.x, b.x); r.y = fmaxf(a.y, b.y); return r;
}
__device__ __forceinline__ f32x2 pmin2(f32x2 a, f32x2 b) {
  f32x2 r; r.x = fminf(a.x, b.x); r.y = fminf(a.y, b.y); return r;
}

__global__ void __launch_bounds__(512) pfn_main(
    const float4* __restrict__ feat, const int* __restrict__ nvox,
    const int* __restrict__ coors, const float* __restrict__ W, int K, int P,
    int cnt, int nblocks, float* __restrict__ partials,
    float4* __restrict__ ext) {
  __shared__ float4 pts[8][2][104];
  __shared__ float red[8][NR];
  const int lane = threadIdx.x & 63;
  const int wid = threadIdx.x >> 6;
  const int hl = lane & 31;
  const int p0 = lane >> 5;  // half id: even/odd point

  const f32x2* W2 = (const f32x2*)W;  // [9][32] channel pairs
  const f32x2 v4 = W2[4 * 32 + hl], v5 = W2[5 * 32 + hl];
  const f32x2 v6 = W2[6 * 32 + hl], v7 = W2[7 * 32 + hl];
  const f32x2 v8 = W2[8 * 32 + hl];
  const f32x2 wx = W2[0 * 32 + hl] + v4 + v7;
  const f32x2 wy = W2[1 * 32 + hl] + v5 + v8;
  const f32x2 wz = W2[2 * 32 + hl] + v6;
  const f32x2 w3 = W2[3 * 32 + hl];

  float q1[4] = {0, 0, 0, 0};
  float q2[10] = {0, 0, 0, 0, 0, 0, 0, 0, 0, 0};
  float S[20];
  float u1[5] = {0, 0, 0, 0, 0};
  float u2[15];
#pragma unroll
  for (int i = 0; i < 20; ++i) S[i] = 0.f;
#pragma unroll
  for (int i = 0; i < 15; ++i) u2[i] = 0.f;

  const int gw = blockIdx.x * 8 + wid;
  const int k0 = gw * cnt;
  const int kend = (k0 + cnt < K) ? k0 + cnt : K;

  if (k0 < kend) {
    const bool hih = (64 + lane) < P;
    size_t base = (size_t)k0 * P;
    float4 f0 = feat[base + lane];
    float4 f1;
    if (hih) f1 = feat[base + 64 + lane];
    int nv = nvox[k0];
    float fcx = (float)coors[k0 * 4 + 3], fcy = (float)coors[k0 * 4 + 2];
    int cur = 0;
    for (int k = k0; k < kend; ++k) {
      // ---- stage to LDS (buffer cur; prior extrema used cur^1) ----
      pts[wid][cur][lane] = f0;
      if (hih) pts[wid][cur][64 + lane] = f1;
      if ((nv & 1) && lane == 0) pts[wid][cur][nv] = f0;  // dup pt0 -> odd slot

      // ---- per-lane stats from registers ----
      float sax = f0.x, say = f0.y, saz = f0.z;
      float svx = 0, svy = 0, svz = 0, svw = 0;
      if (lane < nv) {
        svx = f0.x; svy = f0.y; svz = f0.z; svw = f0.w;
        q2[0] = fmaf(f0.x, f0.x, q2[0]); q2[1] = fmaf(f0.x, f0.y, q2[1]);
        q2[2] = fmaf(f0.x, f0.z, q2[2]); q2[3] = fmaf(f0.x, f0.w, q2[3]);
        q2[4] = fmaf(f0.y, f0.y, q2[4]); q2[5] = fmaf(f0.y, f0.z, q2[5]);
        q2[6] = fmaf(f0.y, f0.w, q2[6]); q2[7] = fmaf(f0.z, f0.z, q2[7]);
        q2[8] = fmaf(f0.z, f0.w, q2[8]); q2[9] = fmaf(f0.w, f0.w, q2[9]);
      }
      if (hih) {
        sax += f1.x; say += f1.y; saz += f1.z;
        if (64 + lane < nv) {
          svx += f1.x; svy += f1.y; svz += f1.z; svw += f1.w;
          q2[0] = fmaf(f1.x, f1.x, q2[0]); q2[1] = fmaf(f1.x, f1.y, q2[1]);
          q2[2] = fmaf(f1.x, f1.z, q2[2]); q2[3] = fmaf(f1.x, f1.w, q2[3]);
          q2[4] = fmaf(f1.y, f1.y, q2[4]); q2[5] = fmaf(f1.y, f1.z, q2[5]);
          q2[6] = fmaf(f1.y, f1.w, q2[6]); q2[7] = fmaf(f1.z, f1.z, q2[7]);
          q2[8] = fmaf(f1.z, f1.w, q2[8]); q2[9] = fmaf(f1.w, f1.w, q2[9]);
        }
      }

      // ---- prefetch next pillar (latency hides under extrema) ----
      float4 f0n, f1n;
      int nvn = nv;
      float fcxn = fcx, fcyn = fcy;
      if (k + 1 < kend) {
        size_t nb = (size_t)(k + 1) * P;
        f0n = feat[nb + lane];
        if (hih) f1n = feat[nb + 64 + lane];
        nvn = nvox[k + 1];
        fcxn = (float)coors[(k + 1) * 4 + 3];
        fcyn = (float)coors[(k + 1) * 4 + 2];
      }

      // ---- 3 interleaved wave reductions (all-P mean sums) ----
      float rx = sax, ry = say, rz = saz;
#pragma unroll
      for (int off = 1; off < 64; off <<= 1) {
        rx += __shfl_xor(rx, off, 64);
        ry += __shfl_xor(ry, off, 64);
        rz += __shfl_xor(rz, off, 64);
      }
      const float nvf = (float)nv, inv = 1.f / nvf;
      const float cx = fcx * 0.2f + 0.1f, cy = fcy * 0.2f - 39.9f;
      const float o0 = -rx * inv, o1 = -ry * inv, o2 = -rz * inv;
      const float o3 = -cx, o4 = -cy;

      // ---- extrema over staged points ----
      const int nvv = nv + (nv & 1);
      f32x2 bm0 = {-3e38f, -3e38f}, bm1 = {-3e38f, -3e38f};
      f32x2 bn0 = {3e38f, 3e38f}, bn1 = {3e38f, 3e38f};
      int p = 0;
      for (; p + 4 <= nvv; p += 4) {
        float4 fa = pts[wid][cur][p + p0];
        float4 fb = pts[wid][cur][p + 2 + p0];
        f32x2 ba = wx * fa.x + wy * fa.y + wz * fa.z + w3 * fa.w;
        f32x2 bb = wx * fb.x + wy * fb.y + wz * fb.z + w3 * fb.w;
        bm0 = pmax2(bm0, ba); bn0 = pmin2(bn0, ba);
        bm1 = pmax2(bm1, bb); bn1 = pmin2(bn1, bb);
      }
      if (p < nvv) {
        float4 fa = pts[wid][cur][p + p0];
        f32x2 ba = wx * fa.x + wy * fa.y + wz * fa.z + w3 * fa.w;
        bm0 = pmax2(bm0, ba); bn0 = pmin2(bn0, ba);
      }
      f32x2 bm = pmax2(bm0, bm1), bn = pmin2(bn0, bn1);
      f32x2 tsw;
      tsw.x = __shfl_xor(bm.x, 32, 64); tsw.y = __shfl_xor(bm.y, 32, 64);
      bm = pmax2(bm, tsw);
      tsw.x = __shfl_xor(bn.x, 32, 64); tsw.y = __shfl_xor(bn.y, 32, 64);
      bn = pmin2(bn, tsw);
      const f32x2 bias = v4 * o0 + v5 * o1 + v6 * o2 + v7 * o3 + v8 * o4;
      f32x2 vmax = bm + bias, vmin = bn + bias;
      if (nv < P) {  // masked rows contribute raw x == 0
        vmax.x = fmaxf(vmax.x, 0.f); vmax.y = fmaxf(vmax.y, 0.f);
        vmin.x = fminf(vmin.x, 0.f); vmin.y = fminf(vmin.y, 0.f);
      }
      if (lane < 32) {
        float4 e; e.x = vmax.x; e.y = vmax.y; e.z = vmin.x; e.w = vmin.y;
        ext[(size_t)k * 32 + hl] = e;
      }

      // ---- stats epilogue (per-lane S, uniform U) ----
      q1[0] += svx; q1[1] += svy; q1[2] += svz; q1[3] += svw;
      const float ov[5] = {o0, o1, o2, o3, o4};
      const float sv[4] = {svx, svy, svz, svw};
#pragma unroll
      for (int a = 0; a < 4; ++a)
#pragma unroll
        for (int b = 0; b < 5; ++b)
          S[a * 5 + b] = fmaf(sv[a], ov[b], S[a * 5 + b]);
      float no[5];
#pragma unroll
      for (int b = 0; b < 5; ++b) { no[b] = nvf * ov[b]; u1[b] += no[b]; }
      int ui = 0;
#pragma unroll
      for (int b = 0; b < 5; ++b)
#pragma unroll
        for (int b2 = b; b2 < 5; ++b2) {
          u2[ui] = fmaf(no[b], ov[b2], u2[ui]);
          ++ui;
        }

      f0 = f0n; f1 = f1n; nv = nvn; fcx = fcxn; fcy = fcyn; cur ^= 1;
    }
  }

  // ---- once-per-wave reduction of the 34 per-lane rows ----
  {
    float a34[34];
#pragma unroll
    for (int i = 0; i < 4; ++i) a34[i] = q1[i];
#pragma unroll
    for (int i = 0; i < 10; ++i) a34[4 + i] = q2[i];
#pragma unroll
    for (int i = 0; i < 20; ++i) a34[14 + i] = S[i];
#pragma unroll
    for (int i = 0; i < 34; ++i) a34[i] = wred_add(a34[i]);
    if (lane == 0) {
#pragma unroll
      for (int i = 0; i < 34; ++i) red[wid][i] = a34[i];
#pragma unroll
      for (int j = 0; j < 5; ++j) red[wid][34 + j] = u1[j];
#pragma unroll
      for (int j = 0; j < 15; ++j) red[wid][39 + j] = u2[j];
    }
  }
  __syncthreads();
  const int t = threadIdx.x;
  if (t < NR) {
    float s = 0.f;
#pragma unroll
    for (int w = 0; w < 8; ++w) s += red[w][t];
    partials[t * nblocks + blockIdx.x] = s;
  }
}

// K2: reduce 54 partial rows (4 thr/row, 8-way ILP), assemble augmented
// moments, per-channel scale/shift. One block x 256 threads.
__global__ void __launch_bounds__(256) pfn_finalize(
    const float* __restrict__ partials, int nblocks,
    const float* __restrict__ W, const float* __restrict__ gamma,
    const float* __restrict__ beta, float invN, float* __restrict__ ss) {
  __shared__ float msum[NR];
  __shared__ float m54[54];
  const int t = threadIdx.x;
  const int m = t >> 2, j = t & 3;
  if (m < NR) {
    const int chunk = nblocks >> 2;
    const float* row = partials + m * nblocks + j * chunk;
    float a0 = 0, a1 = 0, a2 = 0, a3 = 0, a4 = 0, a5 = 0, a6 = 0, a7 = 0;
    int b = 0;
    for (; b + 8 <= chunk; b += 8) {
      a0 += row[b];     a1 += row[b + 1]; a2 += row[b + 2]; a3 += row[b + 3];
      a4 += row[b + 4]; a5 += row[b + 5]; a6 += row[b + 6]; a7 += row[b + 7];
    }
    for (; b < chunk; ++b) a0 += row[b];
    float s = ((a0 + a1) + (a2 + a3)) + ((a4 + a5) + (a6 + a7));
    s += __shfl_xor(s, 1, 64);
    s += __shfl_xor(s, 2, 64);
    if (j == 0) msum[m] = s;
  }
  __syncthreads();
  if (t < 54) {
    float v;
    if (t < 9) {
      const int g = (t < 4) ? t : (t < 7 ? t - 4 : t - 7);
      v = msum[g];
      if (t >= 4) v += msum[34 + (t - 4)];
    } else {
      int r = t - 9, c = 0;
      while (r >= 9 - c) { r -= 9 - c; ++c; }
      const int c2 = c + r;
      const int a = (c < 4) ? c : (c < 7 ? c - 4 : c - 7);
      const int b2 = (c2 < 4) ? c2 : (c2 < 7 ? c2 - 4 : c2 - 7);
      const int lo = a < b2 ? a : b2, hi = a < b2 ? b2 : a;
      v = msum[4 + lo * (9 - lo) / 2 + (hi - lo)];  // 4x4 tri offsets 0/4/7/9
      if (c2 >= 4) v += msum[14 + a * 5 + (c2 - 4)];
      if (c >= 4) v += msum[14 + b2 * 5 + (c - 4)];
      if (c >= 4 && c2 >= 4) {
        const int ua = c - 4, ub = c2 - 4;  // ua <= ub
        v += msum[39 + ua * 5 - ua * (ua - 1) / 2 + (ub - ua)];
      }
    }
    m54[t] = v;
  }
  __syncthreads();
  if (t < 64) {
    float wc[9];
#pragma unroll
    for (int c = 0; c < 9; ++c) wc[c] = W[c * 64 + t];
    float mu = 0.f;
#pragma unroll
    for (int c = 0; c < 9; ++c) mu += m54[c] * invN * wc[c];
    float ex2 = 0.f;
    int idx = 9;
#pragma unroll
    for (int c = 0; c < 9; ++c)
#pragma unroll
      for (int c2 = c; c2 < 9; ++c2) {
        float v = m54[idx] * invN * wc[c] * wc[c2];
        ex2 += (c == c2) ? v : 2.f * v;
        ++idx;
      }
    const float var = ex2 - mu * mu;
    const float scale = gamma[t] * rsqrtf(var + 1e-3f);
    ss[t] = scale;
    ss[64 + t] = beta[t] - mu * scale;
  }
}

// K3: elementwise apply — pick extremum by sign(scale), BN affine + relu.
__global__ void __launch_bounds__(256) pfn_apply(
    const float4* __restrict__ ext, const float* __restrict__ ss, int n,
    f32x2* __restrict__ out) {
  const int t = blockIdx.x * 256 + threadIdx.x;
  if (t >= n) return;
  const int l = t & 31;
  const float4 e = ext[t];
  const f32x2 sc = ((const f32x2*)ss)[l];
  const f32x2 sh = ((const f32x2*)(ss + 64))[l];
  const float v0 = (sc.x >= 0.f) ? e.x : e.z;
  const float v1 = (sc.y >= 0.f) ? e.y : e.w;
  f32x2 o;
  o.x = fmaxf(fmaf(sc.x, v0, sh.x), 0.f);
  o.y = fmaxf(fmaf(sc.y, v1, sh.y), 0.f);
  out[t] = o;
}

extern "C" void kernel_launch(void* const* d_in, const int* in_sizes, int n_in,
                              void* d_out, int out_size, void* d_ws,
                              size_t ws_size, hipStream_t stream) {
  const float4* feat = (const float4*)d_in[0];
  const int* nvox = (const int*)d_in[1];
  const int* coors = (const int*)d_in[2];
  const float* W = (const float*)d_in[3];
  const float* gamma = (const float*)d_in[4];
  const float* beta = (const float*)d_in[5];
  float* out = (float*)d_out;

  const int K = in_sizes[1];
  const int P = in_sizes[0] / (K * 4);

  float* ss = (float*)d_ws;    // [128]: scale, shift
  float* partials = ss + 128;  // [NR * nblk], moment-major
  const int nblk = 512;
  float4* ext = (float4*)(partials + NR * nblk);  // [K*32], 16B-aligned

  const int nwaves = nblk * 8;
  const int cnt = (K + nwaves - 1) / nwaves;  // contiguous pillars per wave

  pfn_main<<<nblk, 512, 0, stream>>>(feat, nvox, coors, W, K, P, cnt, nblk,
                                     partials, ext);
  pfn_finalize<<<1, 256, 0, stream>>>(partials, nblk, W, gamma, beta,
                                      1.0f / (float)((long long)K * P), ss);
  const int n3 = K * 32;
  pfn_apply<<<(n3 + 255) / 256, 256, 0, stream>>>(ext, ss, n3, (f32x2*)out);
}